// Round 15
// baseline (97.338 us; speedup 1.0000x reference)
//
#include <hip/hip_runtime.h>
#include <hip/hip_fp16.h>

// KPConv fused via MFMA for MI355X (gfx950) — round 15.
// B=2, N=32768, K=32 neighbors, S=15 kernel pts, C_in=C_out=128.
//
// = round 14 split architecture (gate kernel -> meta in d_ws; main kernel
// = r11 GEMM body) + two latency fixes in the main kernel:
//  1. phase-2 unroll x4: 16 feature gathers in flight -> one ~700cy L3
//     round instead of two for the common cmax<=4 case.
//  2. B-prefetch ring depth 8 (was 4): covers ~250cy L2 latency at
//     ~30cy/iter -> MFMA loop issue-limited instead of latency-limited.
// Register budget stays under the 128 cap of (512,2): phase2 ~115,
// GEMM ~110. Spill tripwire: WRITE_SIZE must stay 32768 KB.

typedef __attribute__((ext_vector_type(8))) _Float16 f16x8;
typedef __attribute__((ext_vector_type(4))) float f32x4;

constexpr int KS  = 15;      // kernel points
constexpr int C   = 128;     // C_in = C_out
constexpr int P   = 32;      // points per block
constexpr int NPT = 32768;   // points per batch
constexpr int NKS = 60;      // total ksteps (15*128/32)
constexpr int SLOTS = 16;    // max survivors per point   (P(>16) ~ 1e-14)
constexpr int PAIRS = 88;    // max survivors per block   (mean 46, +6.3 sd)
constexpr int MSTRIDE = 5632;  // per-block metadata stride in d_ws

constexpr float R2CUT = 0.0513f;          // beyond: all 15 kw < ~3e-8
constexpr float NEGK  = -801.4972449f;    // -1/(2*0.03^2) * log2(e)

__device__ __forceinline__ unsigned swz(unsigned gi) {
    gi ^= ((gi >> 4) & 3u) << 1;
    gi ^= (gi >> 6) & 1u;
    return gi;
}

// ---- W pack body (16x16x32 B-frag order), shared by both paths ----
__device__ __forceinline__ void wpack_body(int t, const float* __restrict__ W,
                                           unsigned short* __restrict__ Wp) {
    const int fl  = t & 63;
    const int gks = (t >> 6) % NKS;
    const int nt  = t / (NKS * 64);
    const int o     = nt * 16 + (fl & 15);
    const int kbase = gks * 32 + (fl >> 4) * 8;
    __half v[8] __attribute__((aligned(16)));
    #pragma unroll
    for (int j = 0; j < 8; ++j)
        v[j] = __float2half_rn(W[(size_t)(kbase + j) * C + o]);
    *(uint4*)(Wp + (size_t)t * 8) = *(const uint4*)v;
}

__global__ void wpack_kernel(const float* __restrict__ W,
                             unsigned short* __restrict__ Wp) {
    wpack_body(blockIdx.x * 256 + threadIdx.x, W, Wp);
}

// ============ gate kernel: gating + compaction + kw -> meta ============
// meta layout per block (MSTRIDE bytes):
//   [0)    int   cnt[32]            128 B
//   [128)  uchar slotid[32][16]     512 B
//   [640)  int   gslot[32][16]     2048 B
//   [2688) half  kw[88][16]        2816 B   (kw[...][15] unused)
__global__ __launch_bounds__(256)
void gate_kernel(const float* __restrict__ xyz,
                 const int*   __restrict__ nidx,
                 const float* __restrict__ kpts,
                 const float* __restrict__ W,
                 unsigned short* __restrict__ Wp,
                 unsigned char* __restrict__ meta)
{
    __shared__ float  s_ctr[P][3];
    __shared__ float  s_kp[KS][3];
    __shared__ int    s_cnt[P];
    __shared__ int    s_pcnt;
    __shared__ unsigned char s_slotid[P][SLOTS];
    __shared__ int    s_gslot[P][SLOTS];
    __shared__ float4 s_rel[PAIRS];
    __shared__ __half s_kw[PAIRS][16];

    const int tid  = threadIdx.x;
    const int blk  = blockIdx.x;
    const int pt0  = blk * P;
    const int boff = pt0 & NPT;

    if (tid < 128) ((unsigned*)s_slotid)[tid] = 0xFFFFFFFFu;
    ((int*)s_gslot)[tid] = 0; ((int*)s_gslot)[tid + 256] = 0;
    if (tid < P) s_cnt[tid] = 0;
    if (tid == 255) s_pcnt = 0;
    if (tid < P * 3) ((float*)s_ctr)[tid] = xyz[(size_t)pt0 * 3 + tid];
    if (tid >= 128 && tid < 128 + KS * 3)
        ((float*)s_kp)[tid - 128] = kpts[tid - 128];
    __syncthreads();

    // gate 1024 pairs, compact survivors
    #pragma unroll
    for (int i = 0; i < 4; ++i) {
        const int q = tid + 256 * i;
        const int p = q >> 5, k = q & 31;
        const int idx = nidx[(pt0 + p) * 32 + k];
        const float rx = xyz[(boff + idx) * 3 + 0] - s_ctr[p][0];
        const float ry = xyz[(boff + idx) * 3 + 1] - s_ctr[p][1];
        const float rz = xyz[(boff + idx) * 3 + 2] - s_ctr[p][2];
        if (rx * rx + ry * ry + rz * rz <= R2CUT) {
            const int slot = atomicAdd(&s_cnt[p], 1);
            if (slot < SLOTS) {
                const int pid = atomicAdd(&s_pcnt, 1);
                if (pid < PAIRS) {
                    s_slotid[p][slot] = (unsigned char)pid;
                    s_gslot[p][slot] = (boff + idx) << 7;
                    s_rel[pid] = make_float4(rx, ry, rz, 0.f);
                }
            }
        }
    }
    __syncthreads();

    // kw: one (pid, s) per lane
    const int pcnt = min(s_pcnt, PAIRS);
    for (int t = tid; t < pcnt * 16; t += 256) {
        const int pid = t >> 4, s = t & 15;
        if (s < KS) {
            const float4 rel = s_rel[pid];
            const float dx = rel.x - s_kp[s][0];
            const float dy = rel.y - s_kp[s][1];
            const float dz = rel.z - s_kp[s][2];
            const float d2 = dx * dx + dy * dy + dz * dz;
            s_kw[pid][s] = __float2half_rn(exp2f(d2 * NEGK));
        }
    }
    __syncthreads();

    // stream metadata out (coalesced)
    unsigned char* mb = meta + (size_t)blk * MSTRIDE;
    if (tid < 32) ((int*)mb)[tid] = s_cnt[tid];
    if (tid < 128) ((unsigned*)(mb + 128))[tid] = ((unsigned*)s_slotid)[tid];
    #pragma unroll
    for (int i = 0; i < 2; ++i)
        ((int*)(mb + 640))[tid + 256 * i] = ((int*)s_gslot)[tid + 256 * i];
    for (int t = tid; t < 704; t += 256)
        ((unsigned*)(mb + 2688))[t] = ((unsigned*)s_kw)[t];

    // fold in W packing (blocks 0..119)
    if (blk < 120) wpack_body(blk * 256 + tid, W, Wp);
}

// ============ main kernel (r11 body, prologue replaced by copy) ============
__launch_bounds__(512, 2)
__global__ void kpconv_pre(const float* __restrict__ feat,
                           const unsigned short* __restrict__ Wp,
                           const unsigned char* __restrict__ meta,
                           const float* __restrict__ bias,
                           float* __restrict__ out)
{
    __shared__ __align__(16) unsigned short a_lds[2 * 32 * 64 * 8]; // 64 KB
    __shared__ __align__(16) __half2        s_kw2[PAIRS][16];       // 5632 B
    __shared__ int            s_gslot[P][SLOTS];                    // 2048 B
    __shared__ unsigned char  s_slotid[P][SLOTS];                   //  512 B
    __shared__ int            s_cnt[P];

    const int tid = threadIdx.x;
    const int pt0 = blockIdx.x * P;
    const unsigned char* mb = meta + (size_t)blockIdx.x * MSTRIDE;

    // ---- phase 0': coalesced metadata -> LDS ----
    if (tid < 32) s_cnt[tid] = ((const int*)mb)[tid];
    if (tid >= 64 && tid < 192)
        ((unsigned*)s_slotid)[tid - 64] = ((const unsigned*)(mb + 128))[tid - 64];
    ((int*)s_gslot)[tid] = ((const int*)(mb + 640))[tid];
    for (int t = tid; t < 704; t += 512) {
        union { unsigned u; __half h[2]; } cv;
        cv.u = ((const unsigned*)(mb + 2688))[t];
        ((__half2*)s_kw2)[2 * t]     = __half2half2(cv.h[0]);
        ((__half2*)s_kw2)[2 * t + 1] = __half2half2(cv.h[1]);
    }
    __syncthreads();

    const int wv   = tid >> 6;         // 0..7
    const int lane = tid & 63;
    const int pb4  = wv * 4;           // phase-2 point set: 4 per wave
    const int c2   = 2 * lane;         // channel pair

    int cnt_r[4]; int cmax = 0;
    #pragma unroll
    for (int pp = 0; pp < 4; ++pp) {
        int cc = s_cnt[pb4 + pp];
        cc = cc > SLOTS ? SLOTS : cc;
        cnt_r[pp] = __builtin_amdgcn_readfirstlane(cc);
        cmax = max(cmax, cnt_r[pp]);
    }

    // ---- phase 2: single-pass aggregation, unrolled x4, load-first ----
    __half2 agg[4][15];
    #pragma unroll
    for (int pp = 0; pp < 4; ++pp)
        #pragma unroll
        for (int s = 0; s < KS; ++s)
            agg[pp][s] = __float2half2_rn(0.f);

    for (int a = 0; a < cmax; a += 4) {
        float2 fv[4][4]; int pidv[4][4]; bool av[4][4];
        #pragma unroll
        for (int pp = 0; pp < 4; ++pp) {
            #pragma unroll
            for (int u = 0; u < 4; ++u) {
                const int aa = a + u;
                av[pp][u] = false;
                if (aa < cnt_r[pp]) {                // wave-uniform
                    const int pt  = pb4 + pp;
                    const int pid = s_slotid[pt][aa];
                    const int off = s_gslot[pt][aa];
                    if (pid != 0xFF) {
                        pidv[pp][u] = pid;
                        fv[pp][u] = *(const float2*)&feat[off + c2];
                        av[pp][u] = true;
                    }
                }
            }
        }
        #pragma unroll
        for (int pp = 0; pp < 4; ++pp) {
            #pragma unroll
            for (int u = 0; u < 4; ++u) {
                if (av[pp][u]) {
                    const int pid = pidv[pp][u];
                    const __half2 h = __float22half2_rn(fv[pp][u]);
                    union { uint4 v[4]; __half2 h2[16]; } kw;
                    kw.v[0] = *(const uint4*)&s_kw2[pid][0];
                    kw.v[1] = *(const uint4*)&s_kw2[pid][4];
                    kw.v[2] = *(const uint4*)&s_kw2[pid][8];
                    kw.v[3] = *(const uint4*)&s_kw2[pid][12];
                    #pragma unroll
                    for (int s = 0; s < KS; ++s)
                        agg[pp][s] = __hfma2(kw.h2[s], h, agg[pp][s]);
                }
            }
        }
    }

    // ---- swizzled LDS bases ----
    const int q2    = (lane >> 2) & 3;
    const int ksoff = lane >> 4;
    const int dsub  = lane & 3;

    int wbaseA[4], wbaseB[4];
    #pragma unroll
    for (int pp = 0; pp < 4; ++pp) {
        const int r   = pb4 + pp;
        const int wmt = r >> 4;
        const int fl  = (r & 15) + 16 * q2;
        wbaseA[pp] = (int)(swz((unsigned)((wmt * 32 + ksoff) * 64 + fl)) * 4
                           + dsub);
        wbaseB[pp] = (int)(swz((unsigned)((wmt * 28 + ksoff) * 64 + fl)) * 4
                           + dsub);
    }
    int rbA[2][2], rbB[2][2];          // [mt][ks parity] byte offsets
    #pragma unroll
    for (int mt = 0; mt < 2; ++mt)
        #pragma unroll
        for (int par = 0; par < 2; ++par) {
            rbA[mt][par] = (int)(swz((unsigned)((mt * 32 + par) * 64 + lane)) * 16);
            rbB[mt][par] = (int)(swz((unsigned)((mt * 28 + par) * 64 + lane)) * 16);
        }

    const unsigned short* wp = Wp + ((size_t)(wv * NKS) * 64 + lane) * 8;

    f32x4 acc[2] = {};                 // C/D frags: [mt]
    const char* const a_bytes = (const char*)a_lds;

    // B prologue: depth-8 ring in flight before/under the A-writes
    f16x8 bq[8];
    #pragma unroll
    for (int i = 0; i < 8; ++i)
        bq[i] = *(const f16x8*)(wp + i * 512);

    // ---- phase 2.5a: write s0..7 (ks 0..31) ----
    #pragma unroll
    for (int pp = 0; pp < 4; ++pp)
        #pragma unroll
        for (int s = 0; s < 8; ++s) {
            union { __half2 h; unsigned u; } cv; cv.h = agg[pp][s];
            ((unsigned*)a_lds)[wbaseA[pp] + s * 1024] = cv.u;
        }
    __syncthreads();

    // ---- phase 3a: MFMA ks 0..31, depth-8 B ring ----
    #pragma unroll
    for (int ks = 0; ks < 32; ++ks) {
        const f16x8 bf = bq[ks & 7];
        bq[ks & 7] = *(const f16x8*)(wp + (ks + 8) * 512);   // max 39 < 60
        const f16x8 af0 = *(const f16x8*)(a_bytes + rbA[0][ks & 1]
                                          + (ks >> 1) * 2048);
        const f16x8 af1 = *(const f16x8*)(a_bytes + rbA[1][ks & 1]
                                          + (ks >> 1) * 2048);
        acc[0] = __builtin_amdgcn_mfma_f32_16x16x32_f16(af0, bf, acc[0], 0, 0, 0);
        acc[1] = __builtin_amdgcn_mfma_f32_16x16x32_f16(af1, bf, acc[1], 0, 0, 0);
    }
    __syncthreads();

    // ---- phase 2.5b: write s8..14 (ks 32..59 -> local 0..27) ----
    #pragma unroll
    for (int pp = 0; pp < 4; ++pp)
        #pragma unroll
        for (int s = 8; s < 15; ++s) {
            union { __half2 h; unsigned u; } cv; cv.h = agg[pp][s];
            ((unsigned*)a_lds)[wbaseB[pp] + (s - 8) * 1024] = cv.u;
        }
    __syncthreads();

    // ---- phase 3b: MFMA ks 32..59 (ring holds gks 32..39 on entry) ----
    #pragma unroll
    for (int i = 0; i < 28; ++i) {
        const f16x8 bf = bq[i & 7];
        if (i + 8 < 28)
            bq[i & 7] = *(const f16x8*)(wp + (40 + i) * 512);  // gks 40..59
        const f16x8 af0 = *(const f16x8*)(a_bytes + rbB[0][i & 1]
                                          + (i >> 1) * 2048);
        const f16x8 af1 = *(const f16x8*)(a_bytes + rbB[1][i & 1]
                                          + (i >> 1) * 2048);
        acc[0] = __builtin_amdgcn_mfma_f32_16x16x32_f16(af0, bf, acc[0], 0, 0, 0);
        acc[1] = __builtin_amdgcn_mfma_f32_16x16x32_f16(af1, bf, acc[1], 0, 0, 0);
    }

    // ---- epilogue: C/D layout col=lane&15, row=(lane>>4)*4+reg ----
    const int col = lane & 15;
    const int rg  = lane >> 4;
    const int o   = wv * 16 + col;
    const float b = bias[o];
    #pragma unroll
    for (int mt = 0; mt < 2; ++mt) {
        #pragma unroll
        for (int r = 0; r < 4; ++r) {
            const int row = mt * 16 + rg * 4 + r;
            out[((size_t)(pt0 + row) << 7) + o] = acc[mt][r] + b;
        }
    }
}

// ============ fallback: exact r11 fused kernel ============
__launch_bounds__(512, 2)
__global__ void kpconv_fused(const float* __restrict__ xyz,
                             const float* __restrict__ feat,
                             const int*   __restrict__ nidx,
                             const float* __restrict__ kpts,
                             const unsigned short* __restrict__ Wp,
                             const float* __restrict__ bias,
                             float* __restrict__ out)
{
    __shared__ __align__(16) unsigned short a_lds[2 * 32 * 64 * 8];
    __shared__ __align__(16) __half2        s_kw2[PAIRS][16];
    __shared__ int            s_gidx[PAIRS];
    __shared__ unsigned char  s_slotid[P][SLOTS];
    __shared__ int            s_cnt[P];
    __shared__ int            s_pcnt;
    __shared__ float          s_ctr[P][3];
    __shared__ float          s_kp[KS][3];

    float4* const s_rel = reinterpret_cast<float4*>(a_lds);

    const int tid  = threadIdx.x;
    const int pt0  = blockIdx.x * P;
    const int boff = pt0 & NPT;

    if (tid < 128) ((unsigned*)s_slotid)[tid] = 0xFFFFFFFFu;
    if (tid < P) s_cnt[tid] = 0;
    if (tid == 480) s_pcnt = 0;
    if (tid < P * 3) ((float*)s_ctr)[tid] = xyz[(size_t)pt0 * 3 + tid];
    if (tid >= 128 && tid < 128 + KS * 3)
        ((float*)s_kp)[tid - 128] = kpts[tid - 128];
    __syncthreads();

    #pragma unroll
    for (int i = 0; i < 2; ++i) {
        const int q = tid + 512 * i;
        const int p = q >> 5, k = q & 31;
        const int idx = nidx[(pt0 + p) * 32 + k];
        const float rx = xyz[(boff + idx) * 3 + 0] - s_ctr[p][0];
        const float ry = xyz[(boff + idx) * 3 + 1] - s_ctr[p][1];
        const float rz = xyz[(boff + idx) * 3 + 2] - s_ctr[p][2];
        if (rx * rx + ry * ry + rz * rz <= R2CUT) {
            const int slot = atomicAdd(&s_cnt[p], 1);
            if (slot < SLOTS) {
                const int pid = atomicAdd(&s_pcnt, 1);
                if (pid < PAIRS) {
                    s_slotid[p][slot] = (unsigned char)pid;
                    s_gidx[pid] = (boff + idx) << 7;
                    s_rel[pid] = make_float4(rx, ry, rz, 0.f);
                }
            }
        }
    }
    __syncthreads();

    const int wv   = tid >> 6;
    const int lane = tid & 63;
    const int pcnt = __builtin_amdgcn_readfirstlane(min(s_pcnt, PAIRS));

    for (int t = tid; t < pcnt * 16; t += 512) {
        const int pid = t >> 4, s = t & 15;
        if (s < KS) {
            const float4 rel = s_rel[pid];
            const float dx = rel.x - s_kp[s][0];
            const float dy = rel.y - s_kp[s][1];
            const float dz = rel.z - s_kp[s][2];
            const float d2 = dx * dx + dy * dy + dz * dz;
            s_kw2[pid][s] = __half2half2(__float2half_rn(exp2f(d2 * NEGK)));
        } else {
            s_kw2[pid][15] = __float2half2_rn(0.f);
        }
    }
    __syncthreads();

    const int pb4 = wv * 4;
    const int c2  = 2 * lane;

    int cnt_r[4]; int cmax = 0;
    #pragma unroll
    for (int pp = 0; pp < 4; ++pp) {
        int cc = s_cnt[pb4 + pp];
        cc = cc > SLOTS ? SLOTS : cc;
        cnt_r[pp] = __builtin_amdgcn_readfirstlane(cc);
        cmax = max(cmax, cnt_r[pp]);
    }

    __half2 agg[4][15];
    #pragma unroll
    for (int pp = 0; pp < 4; ++pp)
        #pragma unroll
        for (int s = 0; s < KS; ++s)
            agg[pp][s] = __float2half2_rn(0.f);

    for (int a = 0; a < cmax; a += 2) {
        float2 fv[4][2]; int pidv[4][2]; bool av[4][2];
        #pragma unroll
        for (int pp = 0; pp < 4; ++pp) {
            #pragma unroll
            for (int u = 0; u < 2; ++u) {
                const int aa = a + u;
                av[pp][u] = false;
                if (aa < cnt_r[pp]) {
                    const int pid = s_slotid[pb4 + pp][aa];
                    if (pid != 0xFF) {
                        pidv[pp][u] = pid;
                        fv[pp][u] = *(const float2*)&feat[s_gidx[pid] + c2];
                        av[pp][u] = true;
                    }
                }
            }
        }
        #pragma unroll
        for (int pp = 0; pp < 4; ++pp) {
            #pragma unroll
            for (int u = 0; u < 2; ++u) {
                if (av[pp][u]) {
                    const int pid = pidv[pp][u];
                    const __half2 h = __float22half2_rn(fv[pp][u]);
                    union { uint4 v[4]; __half2 h2[16]; } kw;
                    kw.v[0] = *(const uint4*)&s_kw2[pid][0];
                    kw.v[1] = *(const uint4*)&s_kw2[pid][4];
                    kw.v[2] = *(const uint4*)&s_kw2[pid][8];
                    kw.v[3] = *(const uint4*)&s_kw2[pid][12];
                    #pragma unroll
                    for (int s = 0; s < KS; ++s)
                        agg[pp][s] = __hfma2(kw.h2[s], h, agg[pp][s]);
                }
            }
        }
    }

    const int q2    = (lane >> 2) & 3;
    const int ksoff = lane >> 4;
    const int dsub  = lane & 3;

    int wbaseA[4], wbaseB[4];
    #pragma unroll
    for (int pp = 0; pp < 4; ++pp) {
        const int r   = pb4 + pp;
        const int wmt = r >> 4;
        const int fl  = (r & 15) + 16 * q2;
        wbaseA[pp] = (int)(swz((unsigned)((wmt * 32 + ksoff) * 64 + fl)) * 4 + dsub);
        wbaseB[pp] = (int)(swz((unsigned)((wmt * 28 + ksoff) * 64 + fl)) * 4 + dsub);
    }
    int rbA[2][2], rbB[2][2];
    #pragma unroll
    for (int mt = 0; mt < 2; ++mt)
        #pragma unroll
        for (int par = 0; par < 2; ++par) {
            rbA[mt][par] = (int)(swz((unsigned)((mt * 32 + par) * 64 + lane)) * 16);
            rbB[mt][par] = (int)(swz((unsigned)((mt * 28 + par) * 64 + lane)) * 16);
        }

    const unsigned short* wp = Wp + ((size_t)(wv * NKS) * 64 + lane) * 8;

    f32x4 acc[2] = {};
    const char* const a_bytes = (const char*)a_lds;

    f16x8 bq[4];
    #pragma unroll
    for (int i = 0; i < 4; ++i)
        bq[i] = *(const f16x8*)(wp + i * 512);

    #pragma unroll
    for (int pp = 0; pp < 4; ++pp)
        #pragma unroll
        for (int s = 0; s < 8; ++s) {
            union { __half2 h; unsigned u; } cv; cv.h = agg[pp][s];
            ((unsigned*)a_lds)[wbaseA[pp] + s * 1024] = cv.u;
        }
    __syncthreads();

    #pragma unroll
    for (int ks = 0; ks < 32; ++ks) {
        const f16x8 bf = bq[ks & 3];
        bq[ks & 3] = *(const f16x8*)(wp + (ks + 4) * 512);
        const f16x8 af0 = *(const f16x8*)(a_bytes + rbA[0][ks & 1] + (ks >> 1) * 2048);
        const f16x8 af1 = *(const f16x8*)(a_bytes + rbA[1][ks & 1] + (ks >> 1) * 2048);
        acc[0] = __builtin_amdgcn_mfma_f32_16x16x32_f16(af0, bf, acc[0], 0, 0, 0);
        acc[1] = __builtin_amdgcn_mfma_f32_16x16x32_f16(af1, bf, acc[1], 0, 0, 0);
    }
    __syncthreads();

    #pragma unroll
    for (int pp = 0; pp < 4; ++pp)
        #pragma unroll
        for (int s = 8; s < 15; ++s) {
            union { __half2 h; unsigned u; } cv; cv.h = agg[pp][s];
            ((unsigned*)a_lds)[wbaseB[pp] + (s - 8) * 1024] = cv.u;
        }
    __syncthreads();

    #pragma unroll
    for (int i = 0; i < 28; ++i) {
        const f16x8 bf = bq[i & 3];
        if (i + 4 < 28)
            bq[i & 3] = *(const f16x8*)(wp + (36 + i) * 512);
        const f16x8 af0 = *(const f16x8*)(a_bytes + rbB[0][i & 1] + (i >> 1) * 2048);
        const f16x8 af1 = *(const f16x8*)(a_bytes + rbB[1][i & 1] + (i >> 1) * 2048);
        acc[0] = __builtin_amdgcn_mfma_f32_16x16x32_f16(af0, bf, acc[0], 0, 0, 0);
        acc[1] = __builtin_amdgcn_mfma_f32_16x16x32_f16(af1, bf, acc[1], 0, 0, 0);
    }

    const int col = lane & 15;
    const int rg  = lane >> 4;
    const int o   = wv * 16 + col;
    const float b = bias[o];
    #pragma unroll
    for (int mt = 0; mt < 2; ++mt) {
        #pragma unroll
        for (int r = 0; r < 4; ++r) {
            const int row = mt * 16 + rg * 4 + r;
            out[((size_t)(pt0 + row) << 7) + o] = acc[mt][r] + b;
        }
    }
}

extern "C" void kernel_launch(void* const* d_in, const int* in_sizes, int n_in,
                              void* d_out, int out_size, void* d_ws, size_t ws_size,
                              hipStream_t stream)
{
    const float* xyz  = (const float*)d_in[0];
    const float* feat = (const float*)d_in[1];
    const int*   nidx = (const int*)  d_in[2];
    const float* kpts = (const float*)d_in[3];
    const float* W    = (const float*)d_in[4];
    const float* bias = (const float*)d_in[5];
    float* out = (float*)d_out;

    unsigned short* Wp = (unsigned short*)d_ws;              // 491,520 B
    unsigned char*  meta = (unsigned char*)d_ws + 491520;    // 11.5 MB

    const int total_pts = in_sizes[0] / 3;        // 65536
    const int blocks = total_pts / P;             // 2048
    const size_t need = 491520 + (size_t)blocks * MSTRIDE;

    if (ws_size >= need) {
        gate_kernel<<<blocks, 256, 0, stream>>>(xyz, nidx, kpts, W, Wp, meta);
        kpconv_pre<<<blocks, 512, 0, stream>>>(feat, Wp, meta, bias, out);
    } else {
        wpack_kernel<<<120, 256, 0, stream>>>(W, Wp);
        kpconv_fused<<<blocks, 512, 0, stream>>>(xyz, feat, nidx, kpts,
                                                 Wp, bias, out);
    }
}

// Round 16
// 70.302 us; speedup vs baseline: 1.3846x; 1.3846x over previous
//
#include <hip/hip_runtime.h>
#include <hip/hip_fp16.h>

// KPConv fused via MFMA for MI355X (gfx950) — round 16.
// B=2, N=32768, K=32 neighbors, S=15 kernel pts, C_in=C_out=128.
//
// = round 11 (71.5 us, best known) + ONE change: B-prefetch ring depth 8
// (was 4). r15 tried this together with phase-2 unroll x4 and blew the
// 128-reg budget (occupancy 36->20%, regs sourced from unified VGPR/AGPR
// file; 1 block/CU). Here: +16 regs only (est ~80 total), phase 2 stays
// x2-unrolled. Isolates the "MFMA loop is B-L2-latency-limited" theory:
// depth 8 x ~30cy/iter covers the ~250cy L2 latency.
//
// 16x16x32 f16 fragment layouts (HW-verified r2-r14):
//   A/B: lane l holds X[row|col=l&15][k=(l>>4)*8+j]
//   C/D: col=lane&15, row=(lane>>4)*4+reg

typedef __attribute__((ext_vector_type(8))) _Float16 f16x8;
typedef __attribute__((ext_vector_type(4))) float f32x4;

constexpr int KS  = 15;      // kernel points
constexpr int C   = 128;     // C_in = C_out
constexpr int P   = 32;      // points per block
constexpr int NPT = 32768;   // points per batch
constexpr int NKS = 60;      // total ksteps (15*128/32)
constexpr int SLOTS = 16;    // max survivors per point   (P(>16) ~ 1e-14)
constexpr int PAIRS = 88;    // max survivors per block   (mean 46, +6.3 sd)

constexpr float R2CUT = 0.0513f;          // beyond: all 15 kw < ~3e-8
constexpr float NEGK  = -801.4972449f;    // -1/(2*0.03^2) * log2(e)

__device__ __forceinline__ unsigned swz(unsigned gi) {
    gi ^= ((gi >> 4) & 3u) << 1;
    gi ^= (gi >> 6) & 1u;
    return gi;
}

// Pack W[k=1920][o=128] f32 -> Wp[nt 8][gks 60][lane 64][j 8] f16.
// B-frag (16x16x32): lane l holds B[kk = (l>>4)*8 + j][col = l&15].
__global__ void wpack_kernel(const float* __restrict__ W,
                             unsigned short* __restrict__ Wp) {
    const int t   = blockIdx.x * 256 + threadIdx.x;   // 30720 threads
    const int fl  = t & 63;
    const int gks = (t >> 6) % NKS;
    const int nt  = t / (NKS * 64);
    const int o     = nt * 16 + (fl & 15);
    const int kbase = gks * 32 + (fl >> 4) * 8;
    __half v[8] __attribute__((aligned(16)));
    #pragma unroll
    for (int j = 0; j < 8; ++j)
        v[j] = __float2half_rn(W[(size_t)(kbase + j) * C + o]);
    *(uint4*)(Wp + (size_t)t * 8) = *(const uint4*)v;
}

__launch_bounds__(512, 2)
__global__ void kpconv_main(const float* __restrict__ xyz,
                            const float* __restrict__ feat,
                            const int*   __restrict__ nidx,
                            const float* __restrict__ kpts,
                            const unsigned short* __restrict__ Wp,
                            const float* __restrict__ bias,
                            float* __restrict__ out)
{
    // A half-tile: 2 mt x 32 ks x 64 lanes x 16 B = 65536 B
    __shared__ __align__(16) unsigned short a_lds[2 * 32 * 64 * 8];
    __shared__ __align__(16) __half2        s_kw2[PAIRS][16];        // 5632 B
    __shared__ int            s_gidx[PAIRS];                         //  352 B
    __shared__ unsigned char  s_slotid[P][SLOTS];                    //  512 B
    __shared__ int            s_cnt[P];
    __shared__ int            s_pcnt;
    __shared__ float          s_ctr[P][3];
    __shared__ float          s_kp[KS][3];

    // survivor rel-positions alias a_lds (dead after phase 1b)
    float4* const s_rel = reinterpret_cast<float4*>(a_lds);          // 1408 B

    const int tid  = threadIdx.x;
    const int pt0  = blockIdx.x * P;
    const int boff = pt0 & NPT;              // batch row offset (0 or 32768)

    // ---- phase 0 ----
    if (tid < 128) ((unsigned*)s_slotid)[tid] = 0xFFFFFFFFu;  // sentinels
    if (tid < P) s_cnt[tid] = 0;
    if (tid == 480) s_pcnt = 0;
    if (tid < P * 3) ((float*)s_ctr)[tid] = xyz[(size_t)pt0 * 3 + tid];
    if (tid >= 128 && tid < 128 + KS * 3)
        ((float*)s_kp)[tid - 128] = kpts[tid - 128];
    __syncthreads();

    // ---- phase 1: gate 1024 pairs, compact survivors ----
    #pragma unroll
    for (int i = 0; i < 2; ++i) {
        const int q = tid + 512 * i;
        const int p = q >> 5, k = q & 31;
        const int idx = nidx[(pt0 + p) * 32 + k];
        const float rx = xyz[(boff + idx) * 3 + 0] - s_ctr[p][0];
        const float ry = xyz[(boff + idx) * 3 + 1] - s_ctr[p][1];
        const float rz = xyz[(boff + idx) * 3 + 2] - s_ctr[p][2];
        if (rx * rx + ry * ry + rz * rz <= R2CUT) {
            const int slot = atomicAdd(&s_cnt[p], 1);
            if (slot < SLOTS) {
                const int pid = atomicAdd(&s_pcnt, 1);
                if (pid < PAIRS) {
                    s_slotid[p][slot] = (unsigned char)pid;
                    s_gidx[pid] = (boff + idx) << 7;   // feature row offset
                    s_rel[pid] = make_float4(rx, ry, rz, 0.f);
                }
            }
        }
    }
    __syncthreads();

    const int wv   = tid >> 6;         // 0..7
    const int lane = tid & 63;
    const int pcnt = __builtin_amdgcn_readfirstlane(min(s_pcnt, PAIRS));

    // ---- phase 1b: fully parallel kw (one (pid,s) per lane), splat half2 ----
    for (int t = tid; t < pcnt * 16; t += 512) {
        const int pid = t >> 4, s = t & 15;
        if (s < KS) {
            const float4 rel = s_rel[pid];
            const float dx = rel.x - s_kp[s][0];
            const float dy = rel.y - s_kp[s][1];
            const float dz = rel.z - s_kp[s][2];
            const float d2 = dx * dx + dy * dy + dz * dz;
            s_kw2[pid][s] = __half2half2(__float2half_rn(exp2f(d2 * NEGK)));
        } else {
            s_kw2[pid][15] = __float2half2_rn(0.f);
        }
    }
    __syncthreads();   // also: last read of s_rel before a_lds reuse

    const int pb4 = wv * 4;            // phase-2 point set: 4 per wave
    const int c2  = 2 * lane;          // channel pair

    int cnt_r[4]; int cmax = 0;
    #pragma unroll
    for (int pp = 0; pp < 4; ++pp) {
        int cc = s_cnt[pb4 + pp];
        cc = cc > SLOTS ? SLOTS : cc;
        cnt_r[pp] = __builtin_amdgcn_readfirstlane(cc);
        cmax = max(cmax, cnt_r[pp]);
    }

    // ---- phase 2: single-pass aggregation, unrolled x2, load-first ----
    __half2 agg[4][15];
    #pragma unroll
    for (int pp = 0; pp < 4; ++pp)
        #pragma unroll
        for (int s = 0; s < KS; ++s)
            agg[pp][s] = __float2half2_rn(0.f);

    for (int a = 0; a < cmax; a += 2) {
        float2 fv[4][2]; int pidv[4][2]; bool av[4][2];
        #pragma unroll
        for (int pp = 0; pp < 4; ++pp) {
            #pragma unroll
            for (int u = 0; u < 2; ++u) {
                const int aa = a + u;
                av[pp][u] = false;
                if (aa < cnt_r[pp]) {                // wave-uniform
                    const int pid = s_slotid[pb4 + pp][aa];
                    if (pid != 0xFF) {
                        pidv[pp][u] = pid;
                        fv[pp][u] = *(const float2*)&feat[s_gidx[pid] + c2];
                        av[pp][u] = true;
                    }
                }
            }
        }
        #pragma unroll
        for (int pp = 0; pp < 4; ++pp) {
            #pragma unroll
            for (int u = 0; u < 2; ++u) {
                if (av[pp][u]) {
                    const int pid = pidv[pp][u];
                    const __half2 h = __float22half2_rn(fv[pp][u]);
                    union { uint4 v[4]; __half2 h2[16]; } kw;
                    kw.v[0] = *(const uint4*)&s_kw2[pid][0];
                    kw.v[1] = *(const uint4*)&s_kw2[pid][4];
                    kw.v[2] = *(const uint4*)&s_kw2[pid][8];
                    kw.v[3] = *(const uint4*)&s_kw2[pid][12];
                    #pragma unroll
                    for (int s = 0; s < KS; ++s)
                        agg[pp][s] = __hfma2(kw.h2[s], h, agg[pp][s]);
                }
            }
        }
    }

    // ---- swizzled LDS bases (write: word idx; read: byte offset) ----
    const int q2    = (lane >> 2) & 3;
    const int ksoff = lane >> 4;
    const int dsub  = lane & 3;

    int wbaseA[4], wbaseB[4];
    #pragma unroll
    for (int pp = 0; pp < 4; ++pp) {
        const int r   = pb4 + pp;
        const int wmt = r >> 4;
        const int fl  = (r & 15) + 16 * q2;
        wbaseA[pp] = (int)(swz((unsigned)((wmt * 32 + ksoff) * 64 + fl)) * 4
                           + dsub);
        wbaseB[pp] = (int)(swz((unsigned)((wmt * 28 + ksoff) * 64 + fl)) * 4
                           + dsub);
    }
    int rbA[2][2], rbB[2][2];          // [mt][ks parity] byte offsets
    #pragma unroll
    for (int mt = 0; mt < 2; ++mt)
        #pragma unroll
        for (int par = 0; par < 2; ++par) {
            rbA[mt][par] = (int)(swz((unsigned)((mt * 32 + par) * 64 + lane)) * 16);
            rbB[mt][par] = (int)(swz((unsigned)((mt * 28 + par) * 64 + lane)) * 16);
        }

    // per-wave B-fragment base (ntile = wv; each B-frag read once per block)
    const unsigned short* wp = Wp + ((size_t)(wv * NKS) * 64 + lane) * 8;

    f32x4 acc[2] = {};                 // C/D frags: [mt]
    const char* const a_bytes = (const char*)a_lds;

    // B prologue: depth-8 ring in flight before/under the A-writes
    f16x8 bq[8];
    #pragma unroll
    for (int i = 0; i < 8; ++i)
        bq[i] = *(const f16x8*)(wp + i * 512);

    // ---- phase 2.5a: write s0..7 (ks 0..31) ----
    #pragma unroll
    for (int pp = 0; pp < 4; ++pp)
        #pragma unroll
        for (int s = 0; s < 8; ++s) {
            union { __half2 h; unsigned u; } cv; cv.h = agg[pp][s];
            ((unsigned*)a_lds)[wbaseA[pp] + s * 1024] = cv.u;
        }
    __syncthreads();

    // ---- phase 3a: MFMA ks 0..31, depth-8 B ring ----
    #pragma unroll
    for (int ks = 0; ks < 32; ++ks) {
        const f16x8 bf = bq[ks & 7];
        bq[ks & 7] = *(const f16x8*)(wp + (ks + 8) * 512);   // max gks 39 < 60
        const f16x8 af0 = *(const f16x8*)(a_bytes + rbA[0][ks & 1]
                                          + (ks >> 1) * 2048);
        const f16x8 af1 = *(const f16x8*)(a_bytes + rbA[1][ks & 1]
                                          + (ks >> 1) * 2048);
        acc[0] = __builtin_amdgcn_mfma_f32_16x16x32_f16(af0, bf, acc[0], 0, 0, 0);
        acc[1] = __builtin_amdgcn_mfma_f32_16x16x32_f16(af1, bf, acc[1], 0, 0, 0);
    }
    __syncthreads();   // all reads of half A done

    // ---- phase 2.5b: write s8..14 (ks 32..59 -> local 0..27) ----
    #pragma unroll
    for (int pp = 0; pp < 4; ++pp)
        #pragma unroll
        for (int s = 8; s < 15; ++s) {
            union { __half2 h; unsigned u; } cv; cv.h = agg[pp][s];
            ((unsigned*)a_lds)[wbaseB[pp] + (s - 8) * 1024] = cv.u;
        }
    __syncthreads();

    // ---- phase 3b: MFMA ks 32..59 (ring enters with slot j = gks 32+j) ----
    #pragma unroll
    for (int i = 0; i < 28; ++i) {
        const f16x8 bf = bq[i & 7];
        if (i + 8 < 28)
            bq[i & 7] = *(const f16x8*)(wp + (40 + i) * 512);  // gks 40..59
        const f16x8 af0 = *(const f16x8*)(a_bytes + rbB[0][i & 1]
                                          + (i >> 1) * 2048);
        const f16x8 af1 = *(const f16x8*)(a_bytes + rbB[1][i & 1]
                                          + (i >> 1) * 2048);
        acc[0] = __builtin_amdgcn_mfma_f32_16x16x32_f16(af0, bf, acc[0], 0, 0, 0);
        acc[1] = __builtin_amdgcn_mfma_f32_16x16x32_f16(af1, bf, acc[1], 0, 0, 0);
    }

    // ---- epilogue: C/D layout col=lane&15, row=(lane>>4)*4+reg ----
    const int col = lane & 15;
    const int rg  = lane >> 4;
    const int o   = wv * 16 + col;
    const float b = bias[o];
    #pragma unroll
    for (int mt = 0; mt < 2; ++mt) {
        #pragma unroll
        for (int r = 0; r < 4; ++r) {
            const int row = mt * 16 + rg * 4 + r;
            out[((size_t)(pt0 + row) << 7) + o] = acc[mt][r] + b;
        }
    }
}

extern "C" void kernel_launch(void* const* d_in, const int* in_sizes, int n_in,
                              void* d_out, int out_size, void* d_ws, size_t ws_size,
                              hipStream_t stream)
{
    const float* xyz  = (const float*)d_in[0];
    const float* feat = (const float*)d_in[1];
    const int*   nidx = (const int*)  d_in[2];
    const float* kpts = (const float*)d_in[3];
    const float* W    = (const float*)d_in[4];
    const float* bias = (const float*)d_in[5];
    float* out = (float*)d_out;

    unsigned short* Wp = (unsigned short*)d_ws;   // 491,520 B

    wpack_kernel<<<120, 256, 0, stream>>>(W, Wp);

    const int total_pts = in_sizes[0] / 3;        // 65536
    kpconv_main<<<total_pts / P, 512, 0, stream>>>(xyz, feat, nidx, kpts,
                                                   Wp, bias, out);
}